// Round 5
// baseline (258.407 us; speedup 1.0000x reference)
//
#include <hip/hip_runtime.h>
#include <hip/hip_bf16.h>

#define N_NODES 100000
#define N_EDGES 1600000
#define IN_DIM 128
#define HID_DIM 128
#define OUT_DIM 40

#define BSHIFT 9                 // 512 nodes per bucket
#define NBUCK 196                // ceil(100000/512)
#define CHUNK 4096               // edges per scatter/count block
#define NCHUNK ((N_EDGES + CHUNK - 1) / CHUNK)

typedef __attribute__((ext_vector_type(8))) short short8;   // 8 x bf16 (4 VGPRs)
typedef __attribute__((ext_vector_type(4))) float float4v;  // MFMA C/D + float4 loads
typedef __attribute__((ext_vector_type(2))) float f32x2;
typedef __attribute__((ext_vector_type(2))) unsigned int u32x2;
typedef __attribute__((ext_vector_type(4))) unsigned int u32x4;

typedef unsigned char u8;
typedef unsigned short u16;
typedef unsigned int u32;
typedef unsigned long long u64;

__device__ __forceinline__ float bflo(u32 v) { union { u32 u; float f; } c; c.u = v << 16; return c.f; }
__device__ __forceinline__ float bfhi(u32 v) { union { u32 u; float f; } c; c.u = v & 0xffff0000u; return c.f; }
__device__ __forceinline__ u16 f2bf(float f) {  // RNE
    union { float f; u32 u; } c; c.f = f;
    u32 r = c.u + 0x7fffu + ((c.u >> 16) & 1u);
    return (u16)(r >> 16);
}
__device__ __forceinline__ u32 pk(float lo, float hi) {
    return ((u32)f2bf(hi) << 16) | (u32)f2bf(lo);
}

// manual f32 -> fp8 e4m3fn (OCP), RNE, saturating. Used on the dense-2 encode
// path (values may approach the fp8 max; manual clamps to 448).
__device__ __forceinline__ u32 f2fp8(float f) {
    union { float f; u32 u; } c; c.f = f;
    u32 s = (c.u >> 24) & 0x80u;
    u32 a = c.u & 0x7fffffffu;
    u32 code;
    if (a >= 0x3C800000u) {                    // >= 2^-6 : normal range
        if (a > 0x43E00000u) a = 0x43E00000u;  // clamp to 448
        u32 r = a + 0x0007FFFFu + ((a >> 20) & 1u);
        code = (((r >> 23) - 120u) << 3) | ((r >> 20) & 7u);
        if (code > 0x7Eu) code = 0x7Eu;
    } else {                                   // subnormal
        union { u32 u; float f; } d; d.u = a;
        code = (u32)(int)rintf(d.f * 512.0f);
    }
    return s | code;
}

// ---- fused: x convert (bf16 + fp8) + W swizzle-convert + bucket histogram ---

#define XBLKS ((N_NODES * IN_DIM / 4 + 255) / 256)
#define WTRIP1 2048              // 8ct*4ks*64lane per W1 matrix
#define WTRIP2 768               // 3ct*4ks*64lane per W2 matrix (48 padded rows)
#define WBLKS 22                 // ceil((2*2048+2*768)/256)

__global__ __launch_bounds__(256) void k_cvtall(
    const float* __restrict__ x, u16* __restrict__ xb, u32* __restrict__ xb8,
    const float* __restrict__ w1l, const float* __restrict__ w1r,
    const float* __restrict__ w2l, const float* __restrict__ w2r,
    u16* __restrict__ w1lf, u16* __restrict__ w1rf,
    u16* __restrict__ w2lf, u16* __restrict__ w2rf,
    const int* __restrict__ idx, int* __restrict__ bucket_size) {
    __shared__ int cnt[NBUCK];
    int b = blockIdx.x;
    if (b < XBLKS) {
        int i = b * 256 + threadIdx.x;
        if (i < N_NODES * IN_DIM / 4) {
            float4v v = reinterpret_cast<const float4v*>(x)[i];
            u32x2 o;
            o.x = pk(v.x, v.y);
            o.y = pk(v.z, v.w);
            reinterpret_cast<u32x2*>(xb)[i] = o;
            // HW packed fp8 encode (RNE, OCP e4m3fn), x ~ N(0,1) is far from
            // the 448 saturation point.
            u32 r8 = (u32)__builtin_amdgcn_cvt_pk_fp8_f32(v.x, v.y, 0, false);
            r8 = (u32)__builtin_amdgcn_cvt_pk_fp8_f32(v.z, v.w, (int)r8, true);
            xb8[i] = r8;
        }
        return;
    }
    if (b < XBLKS + WBLKS) {
        int i = (b - XBLKS) * 256 + threadIdx.x;   // one fragment (8 elems)
        const float* s; u16* d; int t; int rows;
        if (i < WTRIP1)            { s = w1l; d = w1lf; t = i;                 rows = HID_DIM; }
        else if (i < 2*WTRIP1)     { s = w1r; d = w1rf; t = i - WTRIP1;        rows = HID_DIM; }
        else if (i < 2*WTRIP1+WTRIP2)   { s = w2l; d = w2lf; t = i - 2*WTRIP1; rows = OUT_DIM; }
        else if (i < 2*WTRIP1+2*WTRIP2) { s = w2r; d = w2rf; t = i - 2*WTRIP1-WTRIP2; rows = OUT_DIM; }
        else return;
        int lane = t & 63;
        int ks = (t >> 6) & 3;
        int ct = t >> 8;
        int row = ct * 16 + (lane & 15);
        u32x4 o;
        if (row < rows) {
            const float* sp = s + row * 128;
            if (rows == HID_DIM) {
                // W1: contiguous k-order fragments
                int col = ks * 32 + (lane >> 4) * 8;
                float4v v0 = *reinterpret_cast<const float4v*>(sp + col);
                float4v v1 = *reinterpret_cast<const float4v*>(sp + col + 4);
                o.x = pk(v0.x, v0.y); o.y = pk(v0.z, v0.w);
                o.z = pk(v1.x, v1.y); o.w = pk(v1.z, v1.w);
            } else {
                // W2: sigma-permuted k-order. Fragment elem j holds dim
                // 16*j + (ks*4 + qq) so that the fused dense kernel's h-tile
                // LDS transpose is a pure per-lane short8 write + lane-
                // contiguous read. K-permutation is exact for the GEMM.
                int c0 = ks * 4 + (lane >> 4);
                float f0 = sp[c0];       float f1 = sp[c0 + 16];
                float f2 = sp[c0 + 32];  float f3 = sp[c0 + 48];
                float f4 = sp[c0 + 64];  float f5 = sp[c0 + 80];
                float f6 = sp[c0 + 96];  float f7 = sp[c0 + 112];
                o.x = pk(f0, f1); o.y = pk(f2, f3);
                o.z = pk(f4, f5); o.w = pk(f6, f7);
            }
        } else { o.x = 0; o.y = 0; o.z = 0; o.w = 0; }
        reinterpret_cast<u32x4*>(d)[t] = o;
        return;
    }
    // histogram part
    int t = threadIdx.x;
    for (int i = t; i < NBUCK; i += 256) cnt[i] = 0;
    __syncthreads();
    int base = (b - XBLKS - WBLKS) * CHUNK;
    int n = min(CHUNK, N_EDGES - base);
    for (int i = t; i < n; i += 256)
        atomicAdd(&cnt[idx[N_EDGES + base + i] >> BSHIFT], 1);
    __syncthreads();
    for (int i = t; i < NBUCK; i += 256)
        if (cnt[i]) atomicAdd(&bucket_size[i], cnt[i]);
}

// ---- CSR build: radix partition by dst bucket -------------------------------

__global__ __launch_bounds__(1024) void k_bscatter(const int* __restrict__ idx,
                                                   const int* __restrict__ bucket_size,
                                                   int* __restrict__ bucket_cur,
                                                   u64* __restrict__ rec) {
    __shared__ int cnt[NBUCK], gbase[NBUCK];
    __shared__ int sa[256], sb[256];
    int t = threadIdx.x;
    const int nt = 1024;
    for (int i = t; i < NBUCK; i += nt) cnt[i] = 0;
    __syncthreads();
    int base = blockIdx.x * CHUNK;
    int n = min(CHUNK, N_EDGES - base);
    int eb[4], eq[4];
    u64 er[4];
    #pragma unroll
    for (int k = 0; k < 4; ++k) {
        int i = t + k * nt;
        if (i < n) {
            int srcv = idx[base + i];
            int dstv = idx[N_EDGES + base + i];
            int b = dstv >> BSHIFT;
            eb[k] = b;
            eq[k] = atomicAdd(&cnt[b], 1);
            er[k] = ((u64)(u32)dstv << 32) | (u32)srcv;
        }
    }
    int myv = 0;
    if (t < 256) {
        myv = (t < NBUCK) ? bucket_size[t] : 0;
        sa[t] = myv;
    }
    __syncthreads();
    int *s = sa, *d = sb;
    for (int dd = 1; dd < 256; dd <<= 1) {
        if (t < 256) d[t] = s[t] + ((t >= dd) ? s[t - dd] : 0);
        __syncthreads();
        int* tm = s; s = d; d = tm;
    }
    if (t < NBUCK) {
        int v = cnt[t];
        gbase[t] = v ? (s[t] - myv) + atomicAdd(&bucket_cur[t], v) : 0;
    }
    __syncthreads();
    #pragma unroll
    for (int k = 0; k < 4; ++k) {
        int i = t + k * nt;
        if (i < n) rec[gbase[eb[k]] + eq[k]] = er[k];
    }
}

__global__ __launch_bounds__(1024) void k_bfill(const u64* __restrict__ rec,
                                                const int* __restrict__ bucket_size,
                                                int* __restrict__ row_start,
                                                int* __restrict__ csr) {
    __shared__ int deg[512], cur[512];
    __shared__ int sa[512], sb[512];
    int t = threadIdx.x;
    int nt = blockDim.x;
    int b = blockIdx.x;
    int node0 = b << BSHIFT;
    int nn = min(512, N_NODES - node0);
    int esz = bucket_size[b];
    if (t < 256) sa[t] = (t < NBUCK) ? bucket_size[t] : 0;
    __syncthreads();
    {
        int *s = sa, *d = sb;
        for (int dd = 1; dd < 256; dd <<= 1) {
            if (t < 256) d[t] = s[t] + ((t >= dd) ? s[t - dd] : 0);
            __syncthreads();
            int* tm = s; s = d; d = tm;
        }
        if (t == 0) cur[0] = s[b] - esz;
    }
    __syncthreads();
    int ebase = cur[0];
    __syncthreads();
    for (int i = t; i < 512; i += nt) deg[i] = 0;
    __syncthreads();
    for (int i = t; i < esz; i += nt)
        atomicAdd(&deg[((int)(rec[ebase + i] >> 32)) & 511], 1);
    __syncthreads();
    for (int i = t; i < 512; i += nt) sa[i] = deg[i];
    __syncthreads();
    int *s = sa, *d = sb;
    for (int dd = 1; dd < 512; dd <<= 1) {
        for (int i = t; i < 512; i += nt) d[i] = s[i] + ((i >= dd) ? s[i - dd] : 0);
        __syncthreads();
        int* tm = s; s = d; d = tm;
    }
    for (int i = t; i < 512; i += nt) {
        int excl = s[i] - deg[i];
        cur[i] = excl;
        if (i < nn) row_start[node0 + i] = ebase + excl;
    }
    if (b == NBUCK - 1 && t == 0) row_start[N_NODES] = N_EDGES;
    __syncthreads();
    for (int i = t; i < esz; i += nt) {
        u64 r = rec[ebase + i];
        int dl = ((int)(r >> 32)) & 511;
        int p = atomicAdd(&cur[dl], 1);
        csr[ebase + p] = (int)(r & 0xffffffffu);
    }
}

// ---- Fused aggregation + dense (layers 1+2 projections) ---------------------
// Phase A: each wave mean-aggregates its own 16 dst nodes (4 at a time,
//   16 lanes/row, 4-deep pipelined fp8 gathers) into a 4 KB LDS tile.
//   The tile is written in MFMA A-fragment order with an XOR swizzle
//   (granule ^= node&7, an involution applied on write AND read) — without
//   it the fragment read is a 16-way bank conflict (row stride 256 B).
// Phase B/C: identical to the previous k_dense, but A-fragments come from
//   the LDS tile instead of a 25.6 MB global round-trip. All phases are
//   wave-self-contained: no __syncthreads anywhere.
// Gather (VMEM-bound) and MFMA phases of co-resident waves overlap.

__global__ __launch_bounds__(256) void k_fused(
    const u32x2* __restrict__ fp,     // fp8 x, 16 granules/row
    const int* __restrict__ csr,
    const int* __restrict__ row_start,
    const u16* __restrict__ x,
    const u16* __restrict__ W1lf, const u16* __restrict__ W1rf,
    const u16* __restrict__ W2lf, const u16* __restrict__ W2rf,
    const float* __restrict__ b1,
    u8* __restrict__ y2, u16* __restrict__ z) {
    __shared__ short8 abuf[4][256];         // [wave][node*16 + swz granule] = 16 KB
    __shared__ short8 hbuf[4][4][64];       // [wave][ks][slot] = 16 KB
    int t = threadIdx.x;
    int wave = t >> 6;
    int lane = t & 63;
    int nb = blockIdx.x * 64 + wave * 16;
    int sub = lane >> 4;      // row slot 0..3 within gather group
    int li = lane & 15;       // 8B granule = dims 8li..8li+7

    // ---- phase A: aggregate 16 nodes, 4 per pass ----
    for (int g4 = 0; g4 < 4; ++g4) {
        int j = g4 * 4 + sub;
        int n = nb + j;
        if (n >= N_NODES) n = N_NODES - 1;
        int s = row_start[n];
        int e = row_start[n + 1];
        f32x2 ac0 = {0.f, 0.f}, ac1 = {0.f, 0.f}, ac2 = {0.f, 0.f}, ac3 = {0.f, 0.f};
#define ACC8(v) do { \
        ac0 += __builtin_amdgcn_cvt_pk_f32_fp8((v).x, false); \
        ac1 += __builtin_amdgcn_cvt_pk_f32_fp8((v).x, true);  \
        ac2 += __builtin_amdgcn_cvt_pk_f32_fp8((v).y, false); \
        ac3 += __builtin_amdgcn_cvt_pk_f32_fp8((v).y, true);  \
    } while (0)
        int p = s;
        u32x2 v0, v1, v2, v3;
        if (p + 4 <= e) {
            int j0 = csr[p], j1 = csr[p + 1], j2 = csr[p + 2], j3 = csr[p + 3];
            v0 = fp[j0 * 16 + li]; v1 = fp[j1 * 16 + li];
            v2 = fp[j2 * 16 + li]; v3 = fp[j3 * 16 + li];
        }
        while (p + 8 <= e) {
            int k0 = csr[p + 4], k1 = csr[p + 5], k2 = csr[p + 6], k3 = csr[p + 7];
            u32x2 w0 = fp[k0 * 16 + li], w1 = fp[k1 * 16 + li];
            u32x2 w2 = fp[k2 * 16 + li], w3 = fp[k3 * 16 + li];
            ACC8(v0); ACC8(v1); ACC8(v2); ACC8(v3);
            v0 = w0; v1 = w1; v2 = w2; v3 = w3;
            p += 4;
        }
        if (p + 4 <= e) { ACC8(v0); ACC8(v1); ACC8(v2); ACC8(v3); p += 4; }
        while (p < e) { u32x2 v = fp[csr[p] * 16 + li]; ACC8(v); ++p; }
#undef ACC8
        float sc = 1.0f / (float)max(e - s, 1);
        union { u32x4 u; short8 s8; } o;
        o.u.x = pk(ac0.x * sc, ac0.y * sc);
        o.u.y = pk(ac1.x * sc, ac1.y * sc);
        o.u.z = pk(ac2.x * sc, ac2.y * sc);
        o.u.w = pk(ac3.x * sc, ac3.y * sc);
        abuf[wave][j * 16 + (li ^ (j & 7))] = o.s8;
    }

    // ---- phase B: layer 1 ----
    int q = lane >> 4;
    int m = lane & 15;
    int arow = nb + m;
    if (arow >= N_NODES) arow = N_NODES - 1;

    short8 afr[8];
    #pragma unroll
    for (int ks = 0; ks < 4; ++ks) {
        afr[ks]     = abuf[wave][m * 16 + ((4 * ks + q) ^ (m & 7))];
        afr[4 + ks] = *reinterpret_cast<const short8*>(x + arow * 128 + ks * 32 + q * 8);
    }
    const short8* g0 = reinterpret_cast<const short8*>(W1lf);
    const short8* g1 = reinterpret_cast<const short8*>(W1rf);

    float4v acc[8];
    #pragma unroll
    for (int ct = 0; ct < 8; ++ct) acc[ct] = (float4v){0.f, 0.f, 0.f, 0.f};

    #pragma unroll
    for (int half = 0; half < 2; ++half) {
        const short8* g = half ? g1 : g0;
        #pragma unroll
        for (int ks = 0; ks < 4; ++ks) {
            short8 a = afr[half * 4 + ks];
            #pragma unroll
            for (int ct = 0; ct < 8; ++ct) {
                short8 bfrag = g[(ct * 4 + ks) * 64 + lane];
                acc[ct] = __builtin_amdgcn_mfma_f32_16x16x32_bf16(a, bfrag, acc[ct], 0, 0, 0);
            }
        }
    }

    float bias[8];
    #pragma unroll
    for (int ct = 0; ct < 8; ++ct) bias[ct] = b1[ct * 16 + m];

    float nsq[4] = { 0.f, 0.f, 0.f, 0.f };
    #pragma unroll
    for (int ct = 0; ct < 8; ++ct)
        #pragma unroll
        for (int r = 0; r < 4; ++r) {
            float v = acc[ct][r] + bias[ct];
            acc[ct][r] = v;
            nsq[r] += v * v;
        }
    #pragma unroll
    for (int r = 0; r < 4; ++r) {
        float tt = nsq[r];
        tt += __shfl_xor(tt, 1);
        tt += __shfl_xor(tt, 2);
        tt += __shfl_xor(tt, 4);
        tt += __shfl_xor(tt, 8);
        nsq[r] = 1.0f / fmaxf(sqrtf(tt), 1e-12f);
    }
    // h tile -> LDS in sigma fragment layout: lane (q,m) holds, for each r,
    // the 8 ct-values of row 4q+r at its m. That IS fragment
    // (ks'=m>>2, qq'=m&3, mm'=4q+r), elem j=ct (dim ct*16+m = 16j + ks'*4+qq').
    #pragma unroll
    for (int r = 0; r < 4; ++r) {
        short8 hs;
        #pragma unroll
        for (int ct = 0; ct < 8; ++ct)
            hs[ct] = (short)f2bf(fmaxf(acc[ct][r] * nsq[r], 0.0f));
        hbuf[wave][m >> 2][(m & 3) * 16 + q * 4 + r] = hs;
    }

    // ---- phase C: layer 2 (reads only this wave's hbuf region) ----
    short8 a2[4];
    #pragma unroll
    for (int ks = 0; ks < 4; ++ks) a2[ks] = hbuf[wave][ks][lane];

    const short8* h0 = reinterpret_cast<const short8*>(W2lf);
    const short8* h1 = reinterpret_cast<const short8*>(W2rf);
    float4v accl[3], accr[3];
    #pragma unroll
    for (int ct = 0; ct < 3; ++ct) {
        accl[ct] = (float4v){0.f, 0.f, 0.f, 0.f};
        accr[ct] = (float4v){0.f, 0.f, 0.f, 0.f};
    }
    #pragma unroll
    for (int ks = 0; ks < 4; ++ks) {
        short8 a = a2[ks];
        #pragma unroll
        for (int ct = 0; ct < 3; ++ct) {
            accl[ct] = __builtin_amdgcn_mfma_f32_16x16x32_bf16(a, h0[(ct * 4 + ks) * 64 + lane], accl[ct], 0, 0, 0);
            accr[ct] = __builtin_amdgcn_mfma_f32_16x16x32_bf16(a, h1[(ct * 4 + ks) * 64 + lane], accr[ct], 0, 0, 0);
        }
    }
    #pragma unroll
    for (int r = 0; r < 4; ++r) {
        int node = nb + q * 4 + r;
        if (node < N_NODES) {
            #pragma unroll
            for (int ct = 0; ct < 3; ++ct) {
                int col = ct * 16 + m;
                y2[node * 64 + col] = (u8)f2fp8(accl[ct][r] * 64.0f);
                z[node * 48 + col]  = f2bf(accr[ct][r]);
            }
            y2[node * 64 + 48 + m] = 0;   // zero-pad dims 48..63
        }
    }
}

// ---- Layer-2 aggregation + fused epilogue, 8 nodes/wave, 4-deep pipeline ----
// fp8 y2 rows = 64 B => 8 lanes/row, 8 dims/lane; each lane owns its 8 dims.

__global__ void k_agg2(const u32x2* __restrict__ fp,   // fp8 y2, 8 granules/row
                       const int* __restrict__ csr,
                       const int* __restrict__ row_start,
                       const u16* __restrict__ z,
                       const float* __restrict__ b2,
                       float* __restrict__ out) {
    int lane = threadIdx.x & 63;
    int wave = threadIdx.x >> 6;
    int sub = lane >> 3;      // node within wave 0..7
    int li = lane & 7;        // 8B granule = dims 8li..8li+7
    int n = blockIdx.x * 32 + wave * 8 + sub;
    int s = row_start[n];
    int e = row_start[n + 1];
    f32x2 ac0 = {0.f, 0.f}, ac1 = {0.f, 0.f}, ac2 = {0.f, 0.f}, ac3 = {0.f, 0.f};
#define ACC8(v) do { \
        ac0 += __builtin_amdgcn_cvt_pk_f32_fp8((v).x, false); \
        ac1 += __builtin_amdgcn_cvt_pk_f32_fp8((v).x, true);  \
        ac2 += __builtin_amdgcn_cvt_pk_f32_fp8((v).y, false); \
        ac3 += __builtin_amdgcn_cvt_pk_f32_fp8((v).y, true);  \
    } while (0)
    int p = s;
    u32x2 v0, v1, v2, v3;
    if (p + 4 <= e) {
        int j0 = csr[p], j1 = csr[p + 1], j2 = csr[p + 2], j3 = csr[p + 3];
        v0 = fp[j0 * 8 + li]; v1 = fp[j1 * 8 + li];
        v2 = fp[j2 * 8 + li]; v3 = fp[j3 * 8 + li];
    }
    while (p + 8 <= e) {
        int k0 = csr[p + 4], k1 = csr[p + 5], k2 = csr[p + 6], k3 = csr[p + 7];
        u32x2 w0 = fp[k0 * 8 + li], w1 = fp[k1 * 8 + li];
        u32x2 w2 = fp[k2 * 8 + li], w3 = fp[k3 * 8 + li];
        ACC8(v0); ACC8(v1); ACC8(v2); ACC8(v3);
        v0 = w0; v1 = w1; v2 = w2; v3 = w3;
        p += 4;
    }
    if (p + 4 <= e) { ACC8(v0); ACC8(v1); ACC8(v2); ACC8(v3); p += 4; }
    while (p < e) { u32x2 v = fp[csr[p] * 8 + li]; ACC8(v); ++p; }
#undef ACC8
    float a[8] = { ac0.x, ac0.y, ac1.x, ac1.y, ac2.x, ac2.y, ac3.x, ac3.y };

    // epilogue: each lane owns dims 8li..8li+7 of its node; reductions are
    // xor 1/2/4 within the 8-lane node group. li>=5 lanes contribute zeros.
    float sc = 1.0f / (64.0f * (float)max(e - s, 1));
    float v[8];
    if (li < 5) {
        u32x4 zv = *reinterpret_cast<const u32x4*>(z + n * 48 + li * 8);
        float4v bv0 = *reinterpret_cast<const float4v*>(b2 + li * 8);
        float4v bv1 = *reinterpret_cast<const float4v*>(b2 + li * 8 + 4);
        v[0] = a[0] * sc + bflo(zv.x) + bv0.x;
        v[1] = a[1] * sc + bfhi(zv.x) + bv0.y;
        v[2] = a[2] * sc + bflo(zv.y) + bv0.z;
        v[3] = a[3] * sc + bfhi(zv.y) + bv0.w;
        v[4] = a[4] * sc + bflo(zv.z) + bv1.x;
        v[5] = a[5] * sc + bfhi(zv.z) + bv1.y;
        v[6] = a[6] * sc + bflo(zv.w) + bv1.z;
        v[7] = a[7] * sc + bfhi(zv.w) + bv1.w;
    } else {
        #pragma unroll
        for (int j = 0; j < 8; ++j) v[j] = 0.f;
    }
    float nsq = 0.f;
    #pragma unroll
    for (int j = 0; j < 8; ++j) nsq += v[j] * v[j];
    nsq += __shfl_xor(nsq, 1);
    nsq += __shfl_xor(nsq, 2);
    nsq += __shfl_xor(nsq, 4);
    float rn = 1.0f / fmaxf(sqrtf(nsq), 1e-12f);
    float mv = 0.f;
    #pragma unroll
    for (int j = 0; j < 8; ++j) {
        v[j] = fmaxf(v[j] * rn, 0.f);
        mv = fmaxf(mv, v[j]);
    }
    mv = fmaxf(mv, __shfl_xor(mv, 1));
    mv = fmaxf(mv, __shfl_xor(mv, 2));
    mv = fmaxf(mv, __shfl_xor(mv, 4));
    float se = 0.f;
    if (li < 5) {
        #pragma unroll
        for (int j = 0; j < 8; ++j) se += __expf(v[j] - mv);
    }
    se += __shfl_xor(se, 1);
    se += __shfl_xor(se, 2);
    se += __shfl_xor(se, 4);
    float lse = __logf(se);
    if (li < 5) {
        float4v o0 = { v[0] - mv - lse, v[1] - mv - lse, v[2] - mv - lse, v[3] - mv - lse };
        float4v o1 = { v[4] - mv - lse, v[5] - mv - lse, v[6] - mv - lse, v[7] - mv - lse };
        *reinterpret_cast<float4v*>(out + n * OUT_DIM + li * 8) = o0;
        *reinterpret_cast<float4v*>(out + n * OUT_DIM + li * 8 + 4) = o1;
    }
}

// ---- launch -----------------------------------------------------------------

extern "C" void kernel_launch(void* const* d_in, const int* in_sizes, int n_in,
                              void* d_out, int out_size, void* d_ws, size_t ws_size,
                              hipStream_t stream) {
    const float* x   = (const float*)d_in[0];
    const int*   idx = (const int*)d_in[1];
    const float* W1l = (const float*)d_in[2];
    const float* b1  = (const float*)d_in[3];
    const float* W1r = (const float*)d_in[4];
    const float* W2l = (const float*)d_in[5];
    const float* b2  = (const float*)d_in[6];
    const float* W2r = (const float*)d_in[7];
    float* out = (float*)d_out;

    // Lifetime plan (kernels serialize on one stream):
    //   cvtall:   W xb, xb8            bscatter: W rec       bfill: R rec, W csr
    //   fused:    R xb8,xb,csr  W y2,z   (y2/z live in the old aggb region —
    //             must NOT overlap xb/xb8/csr, all read concurrently)
    //   agg2:     R y2,z,csr  W out
    char* ws = (char*)d_ws;
    int*   bucket_size = (int*)(ws + 0);        // 784 B   } zeroed together
    int*   bucket_cur  = (int*)(ws + 1024);     // 784 B   }
    int*   row_start   = (int*)(ws + 16384);    // (N+1)*4 B
    int*   csr         = (int*)(ws + 1216384);  // 6.4 MB -> ends 7616384
    u16*   xb          = (u16*)(ws + 7616512);  // 25.6 MB bf16(x), read by k_fused
    u8*    y2          = (u8*)(ws + 33216512);  // 6.4 MB  fp8  (old aggb region)
    u16*   z           = (u16*)(ws + 39616512); // 9.6 MB       (old aggb region)
    u64*   rec         = (u64*)(ws + 58816512); // 12.8 MB (dead after k_bfill)
    u32*   xb8         = (u32*)(ws + 71616512); // 12.8 MB fp8(x), read by k_fused
    u16*   W1lf        = (u16*)(ws + 84416512); // 32768 B (frag-linear)
    u16*   W1rf        = (u16*)(ws + 84449280); // 32768 B
    u16*   W2lf        = (u16*)(ws + 84482048); // 12288 B (frag-linear, sigma k-order, 48 rows)
    u16*   W2rf        = (u16*)(ws + 84494336); // 12288 B

    hipMemsetAsync(ws, 0, 1808, stream);   // bucket_size + bucket_cur

    k_cvtall<<<XBLKS + WBLKS + NCHUNK, 256, 0, stream>>>(
        x, xb, xb8, W1l, W1r, W2l, W2r, W1lf, W1rf, W2lf, W2rf, idx, bucket_size);

    k_bscatter<<<NCHUNK, 1024, 0, stream>>>(idx, bucket_size, bucket_cur, rec);
    k_bfill<<<NBUCK, 1024, 0, stream>>>(rec, bucket_size, row_start, csr);

    // fused: layer-1 aggregation (LDS-staged) + dense layers 1/2
    k_fused<<<(N_NODES + 63) / 64, 256, 0, stream>>>(
        (const u32x2*)xb8, csr, row_start, xb, W1lf, W1rf, W2lf, W2rf, b1, y2, z);
    // layer-2 aggregation with fused epilogue, 8 nodes/wave, 4-deep pipeline
    k_agg2<<<N_NODES / 32, 256, 0, stream>>>((const u32x2*)y2, csr, row_start, z, b2, out);
}

// Round 6
// 256.825 us; speedup vs baseline: 1.0062x; 1.0062x over previous
//
#include <hip/hip_runtime.h>
#include <hip/hip_bf16.h>

#define N_NODES 100000
#define N_EDGES 1600000
#define IN_DIM 128
#define HID_DIM 128
#define OUT_DIM 40

#define BSHIFT 9                 // 512 nodes per bucket
#define NBUCK 196                // ceil(100000/512)
#define CHUNK 4096               // edges per scatter/count block
#define NCHUNK ((N_EDGES + CHUNK - 1) / CHUNK)

typedef __attribute__((ext_vector_type(8))) short short8;   // 8 x bf16 (4 VGPRs)
typedef __attribute__((ext_vector_type(4))) float float4v;  // MFMA C/D + float4 loads
typedef __attribute__((ext_vector_type(2))) float f32x2;
typedef __attribute__((ext_vector_type(2))) unsigned int u32x2;
typedef __attribute__((ext_vector_type(4))) unsigned int u32x4;

typedef unsigned char u8;
typedef unsigned short u16;
typedef unsigned int u32;
typedef unsigned long long u64;

__device__ __forceinline__ float bflo(u32 v) { union { u32 u; float f; } c; c.u = v << 16; return c.f; }
__device__ __forceinline__ float bfhi(u32 v) { union { u32 u; float f; } c; c.u = v & 0xffff0000u; return c.f; }
__device__ __forceinline__ u16 f2bf(float f) {  // RNE
    union { float f; u32 u; } c; c.f = f;
    u32 r = c.u + 0x7fffu + ((c.u >> 16) & 1u);
    return (u16)(r >> 16);
}
__device__ __forceinline__ u32 pk(float lo, float hi) {
    return ((u32)f2bf(hi) << 16) | (u32)f2bf(lo);
}

// manual f32 -> fp8 e4m3fn (OCP), RNE, saturating. Used on the dense-2 encode
// path (values may approach the fp8 max; manual clamps to 448).
__device__ __forceinline__ u32 f2fp8(float f) {
    union { float f; u32 u; } c; c.f = f;
    u32 s = (c.u >> 24) & 0x80u;
    u32 a = c.u & 0x7fffffffu;
    u32 code;
    if (a >= 0x3C800000u) {                    // >= 2^-6 : normal range
        if (a > 0x43E00000u) a = 0x43E00000u;  // clamp to 448
        u32 r = a + 0x0007FFFFu + ((a >> 20) & 1u);
        code = (((r >> 23) - 120u) << 3) | ((r >> 20) & 7u);
        if (code > 0x7Eu) code = 0x7Eu;
    } else {                                   // subnormal
        union { u32 u; float f; } d; d.u = a;
        code = (u32)(int)rintf(d.f * 512.0f);
    }
    return s | code;
}

// ---- fused: x convert (bf16 + fp8 planes) + W swizzle + bucket histogram ----

#define XBLKS ((N_NODES * IN_DIM / 4 + 255) / 256)
#define WTRIP1 2048              // 8ct*4ks*64lane per W1 matrix
#define WTRIP2 768               // 3ct*4ks*64lane per W2 matrix (48 padded rows)
#define WBLKS 22                 // ceil((2*2048+2*768)/256)

__global__ __launch_bounds__(256) void k_cvtall(
    const float* __restrict__ x, u16* __restrict__ xb,
    u32* __restrict__ xb8p0, u32* __restrict__ xb8p1,
    const float* __restrict__ w1l, const float* __restrict__ w1r,
    const float* __restrict__ w2l, const float* __restrict__ w2r,
    u16* __restrict__ w1lf, u16* __restrict__ w1rf,
    u16* __restrict__ w2lf, u16* __restrict__ w2rf,
    const int* __restrict__ idx, int* __restrict__ bucket_size) {
    __shared__ int cnt[NBUCK];
    int b = blockIdx.x;
    if (b < XBLKS) {
        int i = b * 256 + threadIdx.x;
        if (i < N_NODES * IN_DIM / 4) {
            float4v v = reinterpret_cast<const float4v*>(x)[i];
            u32x2 o;
            o.x = pk(v.x, v.y);
            o.y = pk(v.z, v.w);
            reinterpret_cast<u32x2*>(xb)[i] = o;
            // HW packed fp8 encode (RNE, OCP e4m3fn). Two half-dim planes so
            // each gather pass has a 6.4 MB working set (per-XCD L2 = 4 MB).
            u32 r8 = (u32)__builtin_amdgcn_cvt_pk_fp8_f32(v.x, v.y, 0, false);
            r8 = (u32)__builtin_amdgcn_cvt_pk_fp8_f32(v.z, v.w, (int)r8, true);
            int node = i >> 5;
            int g = i & 31;                  // 4-byte granule within node row
            if (g < 16) xb8p0[node * 16 + g] = r8;
            else        xb8p1[node * 16 + (g - 16)] = r8;
        }
        return;
    }
    if (b < XBLKS + WBLKS) {
        int i = (b - XBLKS) * 256 + threadIdx.x;   // one fragment (8 elems)
        const float* s; u16* d; int t; int rows;
        if (i < WTRIP1)            { s = w1l; d = w1lf; t = i;                 rows = HID_DIM; }
        else if (i < 2*WTRIP1)     { s = w1r; d = w1rf; t = i - WTRIP1;        rows = HID_DIM; }
        else if (i < 2*WTRIP1+WTRIP2)   { s = w2l; d = w2lf; t = i - 2*WTRIP1; rows = OUT_DIM; }
        else if (i < 2*WTRIP1+2*WTRIP2) { s = w2r; d = w2rf; t = i - 2*WTRIP1-WTRIP2; rows = OUT_DIM; }
        else return;
        int lane = t & 63;
        int ks = (t >> 6) & 3;
        int ct = t >> 8;
        int row = ct * 16 + (lane & 15);
        u32x4 o;
        if (row < rows) {
            const float* sp = s + row * 128;
            if (rows == HID_DIM) {
                // W1: contiguous k-order fragments
                int col = ks * 32 + (lane >> 4) * 8;
                float4v v0 = *reinterpret_cast<const float4v*>(sp + col);
                float4v v1 = *reinterpret_cast<const float4v*>(sp + col + 4);
                o.x = pk(v0.x, v0.y); o.y = pk(v0.z, v0.w);
                o.z = pk(v1.x, v1.y); o.w = pk(v1.z, v1.w);
            } else {
                // W2: sigma-permuted k-order. Fragment elem j holds dim
                // 16*j + (ks*4 + qq) so that the fused dense kernel's h-tile
                // LDS transpose is a pure per-lane short8 write + lane-
                // contiguous read. K-permutation is exact for the GEMM.
                int c0 = ks * 4 + (lane >> 4);
                float f0 = sp[c0];       float f1 = sp[c0 + 16];
                float f2 = sp[c0 + 32];  float f3 = sp[c0 + 48];
                float f4 = sp[c0 + 64];  float f5 = sp[c0 + 80];
                float f6 = sp[c0 + 96];  float f7 = sp[c0 + 112];
                o.x = pk(f0, f1); o.y = pk(f2, f3);
                o.z = pk(f4, f5); o.w = pk(f6, f7);
            }
        } else { o.x = 0; o.y = 0; o.z = 0; o.w = 0; }
        reinterpret_cast<u32x4*>(d)[t] = o;
        return;
    }
    // histogram part
    int t = threadIdx.x;
    for (int i = t; i < NBUCK; i += 256) cnt[i] = 0;
    __syncthreads();
    int base = (b - XBLKS - WBLKS) * CHUNK;
    int n = min(CHUNK, N_EDGES - base);
    for (int i = t; i < n; i += 256)
        atomicAdd(&cnt[idx[N_EDGES + base + i] >> BSHIFT], 1);
    __syncthreads();
    for (int i = t; i < NBUCK; i += 256)
        if (cnt[i]) atomicAdd(&bucket_size[i], cnt[i]);
}

// ---- CSR build: radix partition by dst bucket -------------------------------

__global__ __launch_bounds__(1024) void k_bscatter(const int* __restrict__ idx,
                                                   const int* __restrict__ bucket_size,
                                                   int* __restrict__ bucket_cur,
                                                   u64* __restrict__ rec) {
    __shared__ int cnt[NBUCK], gbase[NBUCK];
    __shared__ int sa[256], sb[256];
    int t = threadIdx.x;
    const int nt = 1024;
    for (int i = t; i < NBUCK; i += nt) cnt[i] = 0;
    __syncthreads();
    int base = blockIdx.x * CHUNK;
    int n = min(CHUNK, N_EDGES - base);
    int eb[4], eq[4];
    u64 er[4];
    #pragma unroll
    for (int k = 0; k < 4; ++k) {
        int i = t + k * nt;
        if (i < n) {
            int srcv = idx[base + i];
            int dstv = idx[N_EDGES + base + i];
            int b = dstv >> BSHIFT;
            eb[k] = b;
            eq[k] = atomicAdd(&cnt[b], 1);
            er[k] = ((u64)(u32)dstv << 32) | (u32)srcv;
        }
    }
    int myv = 0;
    if (t < 256) {
        myv = (t < NBUCK) ? bucket_size[t] : 0;
        sa[t] = myv;
    }
    __syncthreads();
    int *s = sa, *d = sb;
    for (int dd = 1; dd < 256; dd <<= 1) {
        if (t < 256) d[t] = s[t] + ((t >= dd) ? s[t - dd] : 0);
        __syncthreads();
        int* tm = s; s = d; d = tm;
    }
    if (t < NBUCK) {
        int v = cnt[t];
        gbase[t] = v ? (s[t] - myv) + atomicAdd(&bucket_cur[t], v) : 0;
    }
    __syncthreads();
    #pragma unroll
    for (int k = 0; k < 4; ++k) {
        int i = t + k * nt;
        if (i < n) rec[gbase[eb[k]] + eq[k]] = er[k];
    }
}

__global__ __launch_bounds__(1024) void k_bfill(const u64* __restrict__ rec,
                                                const int* __restrict__ bucket_size,
                                                int* __restrict__ row_start,
                                                int* __restrict__ csr) {
    __shared__ int deg[512], cur[512];
    __shared__ int sa[512], sb[512];
    int t = threadIdx.x;
    int nt = blockDim.x;
    int b = blockIdx.x;
    int node0 = b << BSHIFT;
    int nn = min(512, N_NODES - node0);
    int esz = bucket_size[b];
    if (t < 256) sa[t] = (t < NBUCK) ? bucket_size[t] : 0;
    __syncthreads();
    {
        int *s = sa, *d = sb;
        for (int dd = 1; dd < 256; dd <<= 1) {
            if (t < 256) d[t] = s[t] + ((t >= dd) ? s[t - dd] : 0);
            __syncthreads();
            int* tm = s; s = d; d = tm;
        }
        if (t == 0) cur[0] = s[b] - esz;
    }
    __syncthreads();
    int ebase = cur[0];
    __syncthreads();
    for (int i = t; i < 512; i += nt) deg[i] = 0;
    __syncthreads();
    for (int i = t; i < esz; i += nt)
        atomicAdd(&deg[((int)(rec[ebase + i] >> 32)) & 511], 1);
    __syncthreads();
    for (int i = t; i < 512; i += nt) sa[i] = deg[i];
    __syncthreads();
    int *s = sa, *d = sb;
    for (int dd = 1; dd < 512; dd <<= 1) {
        for (int i = t; i < 512; i += nt) d[i] = s[i] + ((i >= dd) ? s[i - dd] : 0);
        __syncthreads();
        int* tm = s; s = d; d = tm;
    }
    for (int i = t; i < 512; i += nt) {
        int excl = s[i] - deg[i];
        cur[i] = excl;
        if (i < nn) row_start[node0 + i] = ebase + excl;
    }
    if (b == NBUCK - 1 && t == 0) row_start[N_NODES] = N_EDGES;
    __syncthreads();
    for (int i = t; i < esz; i += nt) {
        u64 r = rec[ebase + i];
        int dl = ((int)(r >> 32)) & 511;
        int p = atomicAdd(&cur[dl], 1);
        csr[ebase + p] = (int)(r & 0xffffffffu);
    }
}

// ---- Mean aggregation (layer 1): one 64 B half-dim plane per pass -----------
// 8 nodes/wave, 8 lanes/row (8 dims each), 4-deep pipelined gathers. Two
// sequential passes (plane 0: dims 0-63, plane 1: dims 64-127) keep the
// gather working set at 6.4 MB/pass for per-XCD L2 locality.

__global__ __launch_bounds__(256) void k_aggp(
                      const u32x2* __restrict__ fp,    // fp8 plane, 8 granules/row
                      const int* __restrict__ csr,
                      const int* __restrict__ row_start,
                      u16* __restrict__ aggh) {        // aggb + plane*64
    int lane = threadIdx.x & 63;
    int wave = threadIdx.x >> 6;
    int sub = lane >> 3;      // node within wave 0..7
    int li = lane & 7;        // 8B granule = plane dims 8li..8li+7
    int n = blockIdx.x * 32 + wave * 8 + sub;
    int s = row_start[n];
    int e = row_start[n + 1];
    f32x2 ac0 = {0.f, 0.f}, ac1 = {0.f, 0.f}, ac2 = {0.f, 0.f}, ac3 = {0.f, 0.f};
#define ACC8(v) do { \
        ac0 += __builtin_amdgcn_cvt_pk_f32_fp8((v).x, false); \
        ac1 += __builtin_amdgcn_cvt_pk_f32_fp8((v).x, true);  \
        ac2 += __builtin_amdgcn_cvt_pk_f32_fp8((v).y, false); \
        ac3 += __builtin_amdgcn_cvt_pk_f32_fp8((v).y, true);  \
    } while (0)
    int p = s;
    u32x2 v0, v1, v2, v3;
    if (p + 4 <= e) {
        int j0 = csr[p], j1 = csr[p + 1], j2 = csr[p + 2], j3 = csr[p + 3];
        v0 = fp[j0 * 8 + li]; v1 = fp[j1 * 8 + li];
        v2 = fp[j2 * 8 + li]; v3 = fp[j3 * 8 + li];
    }
    while (p + 8 <= e) {
        int k0 = csr[p + 4], k1 = csr[p + 5], k2 = csr[p + 6], k3 = csr[p + 7];
        u32x2 w0 = fp[k0 * 8 + li], w1 = fp[k1 * 8 + li];
        u32x2 w2 = fp[k2 * 8 + li], w3 = fp[k3 * 8 + li];
        ACC8(v0); ACC8(v1); ACC8(v2); ACC8(v3);
        v0 = w0; v1 = w1; v2 = w2; v3 = w3;
        p += 4;
    }
    if (p + 4 <= e) { ACC8(v0); ACC8(v1); ACC8(v2); ACC8(v3); p += 4; }
    while (p < e) { u32x2 v = fp[csr[p] * 8 + li]; ACC8(v); ++p; }
#undef ACC8
    float sc = 1.0f / (float)max(e - s, 1);
    u32x4 o;
    o.x = pk(ac0.x * sc, ac0.y * sc);
    o.y = pk(ac1.x * sc, ac1.y * sc);
    o.z = pk(ac2.x * sc, ac2.y * sc);
    o.w = pk(ac3.x * sc, ac3.y * sc);
    *reinterpret_cast<u32x4*>(aggh + n * 128 + li * 8) = o;
}

// ---- Fused dense: layer-1 linear+norm+relu AND layer-2 projections ----------
// No weight LDS staging (B-fragments are coalesced 16 B/lane reads from the
// frag-linear, L2-resident weight arrays) -> occupancy no longer LDS-capped.
// h never round-trips through global: a per-wave 4 KB LDS transpose turns the
// MFMA C-layout into layer-2 A-fragments (sigma K-permutation makes the write
// one short8 per (lane,r) and the read lane-contiguous). No __syncthreads.
// NOTE: y2/z must NOT alias xb/agg — this kernel reads xb+agg while writing
// y2+z (round-2 lesson: the old dense1/dense2a split allowed that aliasing).

__global__ __launch_bounds__(256) void k_dense(
    const u16* __restrict__ agg, const u16* __restrict__ x,
    const u16* __restrict__ W1lf, const u16* __restrict__ W1rf,
    const u16* __restrict__ W2lf, const u16* __restrict__ W2rf,
    const float* __restrict__ b1,
    u8* __restrict__ y2, u16* __restrict__ z) {
    __shared__ short8 hbuf[4][4][64];       // [wave][ks][slot] = 16 KB
    int t = threadIdx.x;
    int wave = t >> 6;
    int lane = t & 63;
    int nb = blockIdx.x * 64 + wave * 16;
    int q = lane >> 4;
    int m = lane & 15;
    int arow = nb + m;
    if (arow >= N_NODES) arow = N_NODES - 1;

    // ---- phase B: layer 1 ----
    short8 afr[8];
    #pragma unroll
    for (int ks = 0; ks < 4; ++ks) {
        afr[ks]     = *reinterpret_cast<const short8*>(agg + arow * 128 + ks * 32 + q * 8);
        afr[4 + ks] = *reinterpret_cast<const short8*>(x   + arow * 128 + ks * 32 + q * 8);
    }
    const short8* g0 = reinterpret_cast<const short8*>(W1lf);
    const short8* g1 = reinterpret_cast<const short8*>(W1rf);

    float4v acc[8];
    #pragma unroll
    for (int ct = 0; ct < 8; ++ct) acc[ct] = (float4v){0.f, 0.f, 0.f, 0.f};

    #pragma unroll
    for (int half = 0; half < 2; ++half) {
        const short8* g = half ? g1 : g0;
        #pragma unroll
        for (int ks = 0; ks < 4; ++ks) {
            short8 a = afr[half * 4 + ks];
            #pragma unroll
            for (int ct = 0; ct < 8; ++ct) {
                short8 bfrag = g[(ct * 4 + ks) * 64 + lane];
                acc[ct] = __builtin_amdgcn_mfma_f32_16x16x32_bf16(a, bfrag, acc[ct], 0, 0, 0);
            }
        }
    }

    float bias[8];
    #pragma unroll
    for (int ct = 0; ct < 8; ++ct) bias[ct] = b1[ct * 16 + m];

    float nsq[4] = { 0.f, 0.f, 0.f, 0.f };
    #pragma unroll
    for (int ct = 0; ct < 8; ++ct)
        #pragma unroll
        for (int r = 0; r < 4; ++r) {
            float v = acc[ct][r] + bias[ct];
            acc[ct][r] = v;
            nsq[r] += v * v;
        }
    #pragma unroll
    for (int r = 0; r < 4; ++r) {
        float tt = nsq[r];
        tt += __shfl_xor(tt, 1);
        tt += __shfl_xor(tt, 2);
        tt += __shfl_xor(tt, 4);
        tt += __shfl_xor(tt, 8);
        nsq[r] = 1.0f / fmaxf(sqrtf(tt), 1e-12f);
    }
    // h tile -> LDS in sigma fragment layout: lane (q,m) holds, for each r,
    // the 8 ct-values of row 4q+r at its m. That IS fragment
    // (ks'=m>>2, qq'=m&3, mm'=4q+r), elem j=ct (dim ct*16+m = 16j + ks'*4+qq').
    #pragma unroll
    for (int r = 0; r < 4; ++r) {
        short8 hs;
        #pragma unroll
        for (int ct = 0; ct < 8; ++ct)
            hs[ct] = (short)f2bf(fmaxf(acc[ct][r] * nsq[r], 0.0f));
        hbuf[wave][m >> 2][(m & 3) * 16 + q * 4 + r] = hs;
    }

    // ---- phase C: layer 2 (reads only this wave's hbuf region) ----
    short8 a2[4];
    #pragma unroll
    for (int ks = 0; ks < 4; ++ks) a2[ks] = hbuf[wave][ks][lane];

    const short8* h0 = reinterpret_cast<const short8*>(W2lf);
    const short8* h1 = reinterpret_cast<const short8*>(W2rf);
    float4v accl[3], accr[3];
    #pragma unroll
    for (int ct = 0; ct < 3; ++ct) {
        accl[ct] = (float4v){0.f, 0.f, 0.f, 0.f};
        accr[ct] = (float4v){0.f, 0.f, 0.f, 0.f};
    }
    #pragma unroll
    for (int ks = 0; ks < 4; ++ks) {
        short8 a = a2[ks];
        #pragma unroll
        for (int ct = 0; ct < 3; ++ct) {
            accl[ct] = __builtin_amdgcn_mfma_f32_16x16x32_bf16(a, h0[(ct * 4 + ks) * 64 + lane], accl[ct], 0, 0, 0);
            accr[ct] = __builtin_amdgcn_mfma_f32_16x16x32_bf16(a, h1[(ct * 4 + ks) * 64 + lane], accr[ct], 0, 0, 0);
        }
    }
    #pragma unroll
    for (int r = 0; r < 4; ++r) {
        int node = nb + q * 4 + r;
        if (node < N_NODES) {
            #pragma unroll
            for (int ct = 0; ct < 3; ++ct) {
                int col = ct * 16 + m;
                y2[node * 64 + col] = (u8)f2fp8(accl[ct][r] * 64.0f);
                z[node * 48 + col]  = f2bf(accr[ct][r]);
            }
            y2[node * 64 + 48 + m] = 0;   // zero-pad dims 48..63
        }
    }
}

// ---- Layer-2 aggregation + fused epilogue, 8 nodes/wave, 4-deep pipeline ----
// fp8 y2 rows = 64 B => 8 lanes/row, 8 dims/lane; each lane owns its 8 dims.

__global__ void k_agg2(const u32x2* __restrict__ fp,   // fp8 y2, 8 granules/row
                       const int* __restrict__ csr,
                       const int* __restrict__ row_start,
                       const u16* __restrict__ z,
                       const float* __restrict__ b2,
                       float* __restrict__ out) {
    int lane = threadIdx.x & 63;
    int wave = threadIdx.x >> 6;
    int sub = lane >> 3;      // node within wave 0..7
    int li = lane & 7;        // 8B granule = dims 8li..8li+7
    int n = blockIdx.x * 32 + wave * 8 + sub;
    int s = row_start[n];
    int e = row_start[n + 1];
    f32x2 ac0 = {0.f, 0.f}, ac1 = {0.f, 0.f}, ac2 = {0.f, 0.f}, ac3 = {0.f, 0.f};
#define ACC8(v) do { \
        ac0 += __builtin_amdgcn_cvt_pk_f32_fp8((v).x, false); \
        ac1 += __builtin_amdgcn_cvt_pk_f32_fp8((v).x, true);  \
        ac2 += __builtin_amdgcn_cvt_pk_f32_fp8((v).y, false); \
        ac3 += __builtin_amdgcn_cvt_pk_f32_fp8((v).y, true);  \
    } while (0)
    int p = s;
    u32x2 v0, v1, v2, v3;
    if (p + 4 <= e) {
        int j0 = csr[p], j1 = csr[p + 1], j2 = csr[p + 2], j3 = csr[p + 3];
        v0 = fp[j0 * 8 + li]; v1 = fp[j1 * 8 + li];
        v2 = fp[j2 * 8 + li]; v3 = fp[j3 * 8 + li];
    }
    while (p + 8 <= e) {
        int k0 = csr[p + 4], k1 = csr[p + 5], k2 = csr[p + 6], k3 = csr[p + 7];
        u32x2 w0 = fp[k0 * 8 + li], w1 = fp[k1 * 8 + li];
        u32x2 w2 = fp[k2 * 8 + li], w3 = fp[k3 * 8 + li];
        ACC8(v0); ACC8(v1); ACC8(v2); ACC8(v3);
        v0 = w0; v1 = w1; v2 = w2; v3 = w3;
        p += 4;
    }
    if (p + 4 <= e) { ACC8(v0); ACC8(v1); ACC8(v2); ACC8(v3); p += 4; }
    while (p < e) { u32x2 v = fp[csr[p] * 8 + li]; ACC8(v); ++p; }
#undef ACC8
    float a[8] = { ac0.x, ac0.y, ac1.x, ac1.y, ac2.x, ac2.y, ac3.x, ac3.y };

    // epilogue: each lane owns dims 8li..8li+7 of its node; reductions are
    // xor 1/2/4 within the 8-lane node group. li>=5 lanes contribute zeros.
    float sc = 1.0f / (64.0f * (float)max(e - s, 1));
    float v[8];
    if (li < 5) {
        u32x4 zv = *reinterpret_cast<const u32x4*>(z + n * 48 + li * 8);
        float4v bv0 = *reinterpret_cast<const float4v*>(b2 + li * 8);
        float4v bv1 = *reinterpret_cast<const float4v*>(b2 + li * 8 + 4);
        v[0] = a[0] * sc + bflo(zv.x) + bv0.x;
        v[1] = a[1] * sc + bfhi(zv.x) + bv0.y;
        v[2] = a[2] * sc + bflo(zv.y) + bv0.z;
        v[3] = a[3] * sc + bfhi(zv.y) + bv0.w;
        v[4] = a[4] * sc + bflo(zv.z) + bv1.x;
        v[5] = a[5] * sc + bfhi(zv.z) + bv1.y;
        v[6] = a[6] * sc + bflo(zv.w) + bv1.z;
        v[7] = a[7] * sc + bfhi(zv.w) + bv1.w;
    } else {
        #pragma unroll
        for (int j = 0; j < 8; ++j) v[j] = 0.f;
    }
    float nsq = 0.f;
    #pragma unroll
    for (int j = 0; j < 8; ++j) nsq += v[j] * v[j];
    nsq += __shfl_xor(nsq, 1);
    nsq += __shfl_xor(nsq, 2);
    nsq += __shfl_xor(nsq, 4);
    float rn = 1.0f / fmaxf(sqrtf(nsq), 1e-12f);
    float mv = 0.f;
    #pragma unroll
    for (int j = 0; j < 8; ++j) {
        v[j] = fmaxf(v[j] * rn, 0.f);
        mv = fmaxf(mv, v[j]);
    }
    mv = fmaxf(mv, __shfl_xor(mv, 1));
    mv = fmaxf(mv, __shfl_xor(mv, 2));
    mv = fmaxf(mv, __shfl_xor(mv, 4));
    float se = 0.f;
    if (li < 5) {
        #pragma unroll
        for (int j = 0; j < 8; ++j) se += __expf(v[j] - mv);
    }
    se += __shfl_xor(se, 1);
    se += __shfl_xor(se, 2);
    se += __shfl_xor(se, 4);
    float lse = __logf(se);
    if (li < 5) {
        float4v o0 = { v[0] - mv - lse, v[1] - mv - lse, v[2] - mv - lse, v[3] - mv - lse };
        float4v o1 = { v[4] - mv - lse, v[5] - mv - lse, v[6] - mv - lse, v[7] - mv - lse };
        *reinterpret_cast<float4v*>(out + n * OUT_DIM + li * 8) = o0;
        *reinterpret_cast<float4v*>(out + n * OUT_DIM + li * 8 + 4) = o1;
    }
}

// ---- launch -----------------------------------------------------------------

extern "C" void kernel_launch(void* const* d_in, const int* in_sizes, int n_in,
                              void* d_out, int out_size, void* d_ws, size_t ws_size,
                              hipStream_t stream) {
    const float* x   = (const float*)d_in[0];
    const int*   idx = (const int*)d_in[1];
    const float* W1l = (const float*)d_in[2];
    const float* b1  = (const float*)d_in[3];
    const float* W1r = (const float*)d_in[4];
    const float* W2l = (const float*)d_in[5];
    const float* b2  = (const float*)d_in[6];
    const float* W2r = (const float*)d_in[7];
    float* out = (float*)d_out;

    // Lifetime plan (kernels serialize on one stream):
    //   cvtall:   W xb, xb8p0/p1       bscatter: W rec       bfill: R rec, W csr
    //   aggp x2:  R xb8p*,csr  W aggb
    //   dense:    R aggb,xb  W y2,z    (y2/z live in rec+xb8 region — both dead here)
    //   agg2:     R y2,z,csr W out
    char* ws = (char*)d_ws;
    int*   bucket_size = (int*)(ws + 0);        // 784 B   } zeroed together
    int*   bucket_cur  = (int*)(ws + 1024);     // 784 B   }
    int*   row_start   = (int*)(ws + 16384);    // (N+1)*4 B
    int*   csr         = (int*)(ws + 1216384);  // 6.4 MB -> ends 7616384
    u16*   xb          = (u16*)(ws + 7616512);  // 25.6 MB bf16(x), read by k_dense
    u16*   aggb        = (u16*)(ws + 33216512); // 25.6 MB (dead after k_dense)
    u64*   rec         = (u64*)(ws + 58816512); // 12.8 MB (dead after k_bfill)
    u32*   xb8p0       = (u32*)(ws + 71616512); // 6.4 MB fp8(x) dims 0-63  (dead after aggp)
    u32*   xb8p1       = (u32*)(ws + 78016512); // 6.4 MB fp8(x) dims 64-127 (dead after aggp)
    u8*    y2          = (u8*)(ws + 58816512);  // 6.4 MB  fp8 (over rec, dead)
    u16*   z           = (u16*)(ws + 65216512); // 9.6 MB  (rec tail + xb8p0 head, both dead)
    u16*   W1lf        = (u16*)(ws + 84416512); // 32768 B (frag-linear)
    u16*   W1rf        = (u16*)(ws + 84449280); // 32768 B
    u16*   W2lf        = (u16*)(ws + 84482048); // 12288 B (frag-linear, sigma k-order, 48 rows)
    u16*   W2rf        = (u16*)(ws + 84494336); // 12288 B

    hipMemsetAsync(ws, 0, 1808, stream);   // bucket_size + bucket_cur

    k_cvtall<<<XBLKS + WBLKS + NCHUNK, 256, 0, stream>>>(
        x, xb, xb8p0, xb8p1, W1l, W1r, W2l, W2r, W1lf, W1rf, W2lf, W2rf, idx, bucket_size);

    k_bscatter<<<NCHUNK, 1024, 0, stream>>>(idx, bucket_size, bucket_cur, rec);
    k_bfill<<<NBUCK, 1024, 0, stream>>>(rec, bucket_size, row_start, csr);

    // layer 1 aggregation: two half-dim plane passes (L2-sized working set)
    k_aggp<<<N_NODES / 32, 256, 0, stream>>>((const u32x2*)xb8p0, csr, row_start, aggb);
    k_aggp<<<N_NODES / 32, 256, 0, stream>>>((const u32x2*)xb8p1, csr, row_start, aggb + 64);
    // fused dense: layer-1 linear+norm+relu -> LDS -> layer-2 projections
    k_dense<<<(N_NODES + 63) / 64, 256, 0, stream>>>(aggb, xb, W1lf, W1rf, W2lf, W2rf, b1, y2, z);
    // layer-2 aggregation with fused epilogue, 8 nodes/wave, 4-deep pipeline
    k_agg2<<<N_NODES / 32, 256, 0, stream>>>((const u32x2*)y2, csr, row_start, z, b2, out);
}

// Round 8
// 239.924 us; speedup vs baseline: 1.0770x; 1.0704x over previous
//
#include <hip/hip_runtime.h>
#include <hip/hip_bf16.h>

#define N_NODES 100000
#define N_EDGES 1600000
#define IN_DIM 128
#define HID_DIM 128
#define OUT_DIM 40

#define BSHIFT 9                 // 512 nodes per bucket
#define NBUCK 196                // ceil(100000/512)
#define CHUNK 4096               // edges per scatter/count block
#define NCHUNK ((N_EDGES + CHUNK - 1) / CHUNK)

typedef __attribute__((ext_vector_type(8))) short short8;   // 8 x bf16 (4 VGPRs)
typedef __attribute__((ext_vector_type(4))) float float4v;  // MFMA C/D + float4 loads
typedef __attribute__((ext_vector_type(2))) float f32x2;
typedef __attribute__((ext_vector_type(2))) unsigned int u32x2;
typedef __attribute__((ext_vector_type(4))) unsigned int u32x4;

typedef unsigned char u8;
typedef unsigned short u16;
typedef unsigned int u32;
typedef unsigned long long u64;

__device__ __forceinline__ float bflo(u32 v) { union { u32 u; float f; } c; c.u = v << 16; return c.f; }
__device__ __forceinline__ float bfhi(u32 v) { union { u32 u; float f; } c; c.u = v & 0xffff0000u; return c.f; }
__device__ __forceinline__ u16 f2bf(float f) {  // RNE
    union { float f; u32 u; } c; c.f = f;
    u32 r = c.u + 0x7fffu + ((c.u >> 16) & 1u);
    return (u16)(r >> 16);
}
__device__ __forceinline__ u32 pk(float lo, float hi) {
    return ((u32)f2bf(hi) << 16) | (u32)f2bf(lo);
}

// manual f32 -> fp8 e4m3fn (OCP), RNE, saturating. Used on the dense-2 encode
// path (values may approach the fp8 max; manual clamps to 448).
__device__ __forceinline__ u32 f2fp8(float f) {
    union { float f; u32 u; } c; c.f = f;
    u32 s = (c.u >> 24) & 0x80u;
    u32 a = c.u & 0x7fffffffu;
    u32 code;
    if (a >= 0x3C800000u) {                    // >= 2^-6 : normal range
        if (a > 0x43E00000u) a = 0x43E00000u;  // clamp to 448
        u32 r = a + 0x0007FFFFu + ((a >> 20) & 1u);
        code = (((r >> 23) - 120u) << 3) | ((r >> 20) & 7u);
        if (code > 0x7Eu) code = 0x7Eu;
    } else {                                   // subnormal
        union { u32 u; float f; } d; d.u = a;
        code = (u32)(int)rintf(d.f * 512.0f);
    }
    return s | code;
}

// ---- tiny standalone histogram (enables bscatter to overlap conversions) ----

__global__ __launch_bounds__(256) void k_hist(const int* __restrict__ idx,
                                              int* __restrict__ bucket_size) {
    __shared__ int cnt[NBUCK];
    int t = threadIdx.x;
    for (int i = t; i < NBUCK; i += 256) cnt[i] = 0;
    __syncthreads();
    int base = blockIdx.x * CHUNK;
    int n = min(CHUNK, N_EDGES - base);
    for (int i = t; i < n; i += 256)
        atomicAdd(&cnt[idx[N_EDGES + base + i] >> BSHIFT], 1);
    __syncthreads();
    for (int i = t; i < NBUCK; i += 256)
        if (cnt[i]) atomicAdd(&bucket_size[i], cnt[i]);
}

// ---- merged launch: radix bucket-scatter + x convert + W swizzle ------------
// bscatter blocks come FIRST in the grid (critical path, starts immediately);
// the 3131 conversion blocks backfill idle CUs. Conversion outputs are not
// consumed until k_agg/k_dense, two launches later.

#define XB4 ((N_NODES * IN_DIM / 4 + 1023) / 1024)   // x-convert blocks @1024
#define WTRIP1 2048              // 8ct*4ks*64lane per W1 matrix
#define WTRIP2 768               // 3ct*4ks*64lane per W2 matrix (48 padded rows)
#define WTOT   (2*WTRIP1 + 2*WTRIP2)
#define WB4    ((WTOT + 1023) / 1024)                // weight-convert blocks @1024

__global__ __launch_bounds__(1024) void k_cvtsc(
    const float* __restrict__ x, u16* __restrict__ xb, u32* __restrict__ xb8,
    const float* __restrict__ w1l, const float* __restrict__ w1r,
    const float* __restrict__ w2l, const float* __restrict__ w2r,
    u16* __restrict__ w1lf, u16* __restrict__ w1rf,
    u16* __restrict__ w2lf, u16* __restrict__ w2rf,
    const int* __restrict__ idx,
    const int* __restrict__ bucket_size,
    int* __restrict__ bucket_cur,
    u64* __restrict__ rec) {
    __shared__ int cnt[NBUCK], gbase[NBUCK];
    __shared__ int sa[256], sb[256];
    int b = blockIdx.x;
    int t = threadIdx.x;
    if (b < NCHUNK) {
        // ---- bucket scatter chunk (identical to the proven k_bscatter) ----
        const int nt = 1024;
        for (int i = t; i < NBUCK; i += nt) cnt[i] = 0;
        __syncthreads();
        int base = b * CHUNK;
        int n = min(CHUNK, N_EDGES - base);
        int eb[4], eq[4];
        u64 er[4];
        #pragma unroll
        for (int k = 0; k < 4; ++k) {
            int i = t + k * nt;
            if (i < n) {
                int srcv = idx[base + i];
                int dstv = idx[N_EDGES + base + i];
                int bb = dstv >> BSHIFT;
                eb[k] = bb;
                eq[k] = atomicAdd(&cnt[bb], 1);
                er[k] = ((u64)(u32)dstv << 32) | (u32)srcv;
            }
        }
        int myv = 0;
        if (t < 256) {
            myv = (t < NBUCK) ? bucket_size[t] : 0;
            sa[t] = myv;
        }
        __syncthreads();
        int *s = sa, *d = sb;
        for (int dd = 1; dd < 256; dd <<= 1) {
            if (t < 256) d[t] = s[t] + ((t >= dd) ? s[t - dd] : 0);
            __syncthreads();
            int* tm = s; s = d; d = tm;
        }
        if (t < NBUCK) {
            int v = cnt[t];
            gbase[t] = v ? (s[t] - myv) + atomicAdd(&bucket_cur[t], v) : 0;
        }
        __syncthreads();
        #pragma unroll
        for (int k = 0; k < 4; ++k) {
            int i = t + k * nt;
            if (i < n) rec[gbase[eb[k]] + eq[k]] = er[k];
        }
        return;
    }
    if (b < NCHUNK + XB4) {
        // ---- x convert: bf16 + fp8 ----
        int i = (b - NCHUNK) * 1024 + t;
        if (i < N_NODES * IN_DIM / 4) {
            float4v v = reinterpret_cast<const float4v*>(x)[i];
            u32x2 o;
            o.x = pk(v.x, v.y);
            o.y = pk(v.z, v.w);
            reinterpret_cast<u32x2*>(xb)[i] = o;
            // HW packed fp8 encode (RNE, OCP e4m3fn); x ~ N(0,1) is far from
            // the 448 saturation point.
            u32 r8 = (u32)__builtin_amdgcn_cvt_pk_fp8_f32(v.x, v.y, 0, false);
            r8 = (u32)__builtin_amdgcn_cvt_pk_fp8_f32(v.z, v.w, (int)r8, true);
            xb8[i] = r8;
        }
        return;
    }
    // ---- weight swizzle-convert ----
    {
        int i = (b - NCHUNK - XB4) * 1024 + t;   // one fragment (8 elems)
        const float* s; u16* d; int ti; int rows;
        if (i < WTRIP1)                 { s = w1l; d = w1lf; ti = i;                   rows = HID_DIM; }
        else if (i < 2*WTRIP1)          { s = w1r; d = w1rf; ti = i - WTRIP1;          rows = HID_DIM; }
        else if (i < 2*WTRIP1+WTRIP2)   { s = w2l; d = w2lf; ti = i - 2*WTRIP1;        rows = OUT_DIM; }
        else if (i < WTOT)              { s = w2r; d = w2rf; ti = i - 2*WTRIP1-WTRIP2; rows = OUT_DIM; }
        else return;
        int lane = ti & 63;
        int ks = (ti >> 6) & 3;
        int ct = ti >> 8;
        int row = ct * 16 + (lane & 15);
        u32x4 o;
        if (row < rows) {
            const float* sp = s + row * 128;
            if (rows == HID_DIM) {
                // W1: contiguous k-order fragments
                int col = ks * 32 + (lane >> 4) * 8;
                float4v v0 = *reinterpret_cast<const float4v*>(sp + col);
                float4v v1 = *reinterpret_cast<const float4v*>(sp + col + 4);
                o.x = pk(v0.x, v0.y); o.y = pk(v0.z, v0.w);
                o.z = pk(v1.x, v1.y); o.w = pk(v1.z, v1.w);
            } else {
                // W2: sigma-permuted k-order. Fragment elem j holds dim
                // 16*j + (ks*4 + qq) so that k_dense's h-tile LDS transpose is
                // a pure per-lane short8 write + lane-contiguous read.
                // K-permutation is exact for the GEMM.
                int c0 = ks * 4 + (lane >> 4);
                float f0 = sp[c0];       float f1 = sp[c0 + 16];
                float f2 = sp[c0 + 32];  float f3 = sp[c0 + 48];
                float f4 = sp[c0 + 64];  float f5 = sp[c0 + 80];
                float f6 = sp[c0 + 96];  float f7 = sp[c0 + 112];
                o.x = pk(f0, f1); o.y = pk(f2, f3);
                o.z = pk(f4, f5); o.w = pk(f6, f7);
            }
        } else { o.x = 0; o.y = 0; o.z = 0; o.w = 0; }
        reinterpret_cast<u32x4*>(d)[ti] = o;
    }
}

// ---- CSR build: per-node sort within bucket ---------------------------------

__global__ __launch_bounds__(1024) void k_bfill(const u64* __restrict__ rec,
                                                const int* __restrict__ bucket_size,
                                                int* __restrict__ row_start,
                                                int* __restrict__ csr) {
    __shared__ int deg[512], cur[512];
    __shared__ int sa[512], sb[512];
    int t = threadIdx.x;
    int nt = blockDim.x;
    int b = blockIdx.x;
    int node0 = b << BSHIFT;
    int nn = min(512, N_NODES - node0);
    int esz = bucket_size[b];
    if (t < 256) sa[t] = (t < NBUCK) ? bucket_size[t] : 0;
    __syncthreads();
    {
        int *s = sa, *d = sb;
        for (int dd = 1; dd < 256; dd <<= 1) {
            if (t < 256) d[t] = s[t] + ((t >= dd) ? s[t - dd] : 0);
            __syncthreads();
            int* tm = s; s = d; d = tm;
        }
        if (t == 0) cur[0] = s[b] - esz;
    }
    __syncthreads();
    int ebase = cur[0];
    __syncthreads();
    for (int i = t; i < 512; i += nt) deg[i] = 0;
    __syncthreads();
    for (int i = t; i < esz; i += nt)
        atomicAdd(&deg[((int)(rec[ebase + i] >> 32)) & 511], 1);
    __syncthreads();
    for (int i = t; i < 512; i += nt) sa[i] = deg[i];
    __syncthreads();
    int *s = sa, *d = sb;
    for (int dd = 1; dd < 512; dd <<= 1) {
        for (int i = t; i < 512; i += nt) d[i] = s[i] + ((i >= dd) ? s[i - dd] : 0);
        __syncthreads();
        int* tm = s; s = d; d = tm;
    }
    for (int i = t; i < 512; i += nt) {
        int excl = s[i] - deg[i];
        cur[i] = excl;
        if (i < nn) row_start[node0 + i] = ebase + excl;
    }
    if (b == NBUCK - 1 && t == 0) row_start[N_NODES] = N_EDGES;
    __syncthreads();
    for (int i = t; i < esz; i += nt) {
        u64 r = rec[ebase + i];
        int dl = ((int)(r >> 32)) & 511;
        int p = atomicAdd(&cur[dl], 1);
        csr[ebase + p] = (int)(r & 0xffffffffu);
    }
}

// ---- Mean aggregation (layer 1): fp8 table, 4 nodes/wave, 4-deep pipeline ---
// 128 B rows, 16 lanes/row (8 dims each), no cross-lane reduce.

__global__ void k_agg(const u32x2* __restrict__ fp,    // fp8 feat, 16 granules/row
                      const int* __restrict__ csr,
                      const int* __restrict__ row_start,
                      u16* __restrict__ agg) {
    int lane = threadIdx.x & 63;
    int wave = threadIdx.x >> 6;
    int sub = lane >> 4;      // node within wave 0..3
    int li = lane & 15;       // 8B granule = dims 8li..8li+7
    int n = blockIdx.x * 16 + wave * 4 + sub;
    int s = row_start[n];
    int e = row_start[n + 1];
    f32x2 ac0 = {0.f, 0.f}, ac1 = {0.f, 0.f}, ac2 = {0.f, 0.f}, ac3 = {0.f, 0.f};
#define ACC8(v) do { \
        ac0 += __builtin_amdgcn_cvt_pk_f32_fp8((v).x, false); \
        ac1 += __builtin_amdgcn_cvt_pk_f32_fp8((v).x, true);  \
        ac2 += __builtin_amdgcn_cvt_pk_f32_fp8((v).y, false); \
        ac3 += __builtin_amdgcn_cvt_pk_f32_fp8((v).y, true);  \
    } while (0)
    int p = s;
    u32x2 v0, v1, v2, v3;
    if (p + 4 <= e) {
        int j0 = csr[p], j1 = csr[p + 1], j2 = csr[p + 2], j3 = csr[p + 3];
        v0 = fp[j0 * 16 + li]; v1 = fp[j1 * 16 + li];
        v2 = fp[j2 * 16 + li]; v3 = fp[j3 * 16 + li];
    }
    while (p + 8 <= e) {
        int k0 = csr[p + 4], k1 = csr[p + 5], k2 = csr[p + 6], k3 = csr[p + 7];
        u32x2 w0 = fp[k0 * 16 + li], w1 = fp[k1 * 16 + li];
        u32x2 w2 = fp[k2 * 16 + li], w3 = fp[k3 * 16 + li];
        ACC8(v0); ACC8(v1); ACC8(v2); ACC8(v3);
        v0 = w0; v1 = w1; v2 = w2; v3 = w3;
        p += 4;
    }
    if (p + 4 <= e) { ACC8(v0); ACC8(v1); ACC8(v2); ACC8(v3); p += 4; }
    while (p < e) { u32x2 v = fp[csr[p] * 16 + li]; ACC8(v); ++p; }
#undef ACC8
    float sc = 1.0f / (float)max(e - s, 1);
    u32x4 o;
    o.x = pk(ac0.x * sc, ac0.y * sc);
    o.y = pk(ac1.x * sc, ac1.y * sc);
    o.z = pk(ac2.x * sc, ac2.y * sc);
    o.w = pk(ac3.x * sc, ac3.y * sc);
    *reinterpret_cast<u32x4*>(agg + n * 128 + li * 8) = o;
}

// ---- Fused dense: layer-1 linear+norm+relu AND layer-2 projections ----------
// No weight LDS staging (B-fragments are coalesced 16 B/lane reads from the
// frag-linear, L2-resident weight arrays) -> occupancy no longer LDS-capped.
// h never round-trips through global: a per-wave 4 KB LDS transpose turns the
// MFMA C-layout into layer-2 A-fragments (sigma K-permutation makes the write
// one short8 per (lane,r) and the read lane-contiguous). No __syncthreads.
// NOTE: y2/z must NOT alias xb/agg — this kernel reads xb+agg while writing
// y2+z (round-2 lesson).

__global__ __launch_bounds__(256) void k_dense(
    const u16* __restrict__ agg, const u16* __restrict__ x,
    const u16* __restrict__ W1lf, const u16* __restrict__ W1rf,
    const u16* __restrict__ W2lf, const u16* __restrict__ W2rf,
    const float* __restrict__ b1,
    u8* __restrict__ y2, u16* __restrict__ z) {
    __shared__ short8 hbuf[4][4][64];       // [wave][ks][slot] = 16 KB
    int t = threadIdx.x;
    int wave = t >> 6;
    int lane = t & 63;
    int nb = blockIdx.x * 64 + wave * 16;
    int q = lane >> 4;
    int m = lane & 15;
    int arow = nb + m;
    if (arow >= N_NODES) arow = N_NODES - 1;

    // ---- phase B: layer 1 ----
    short8 afr[8];
    #pragma unroll
    for (int ks = 0; ks < 4; ++ks) {
        afr[ks]     = *reinterpret_cast<const short8*>(agg + arow * 128 + ks * 32 + q * 8);
        afr[4 + ks] = *reinterpret_cast<const short8*>(x   + arow * 128 + ks * 32 + q * 8);
    }
    const short8* g0 = reinterpret_cast<const short8*>(W1lf);
    const short8* g1 = reinterpret_cast<const short8*>(W1rf);

    float4v acc[8];
    #pragma unroll
    for (int ct = 0; ct < 8; ++ct) acc[ct] = (float4v){0.f, 0.f, 0.f, 0.f};

    #pragma unroll
    for (int half = 0; half < 2; ++half) {
        const short8* g = half ? g1 : g0;
        #pragma unroll
        for (int ks = 0; ks < 4; ++ks) {
            short8 a = afr[half * 4 + ks];
            #pragma unroll
            for (int ct = 0; ct < 8; ++ct) {
                short8 bfrag = g[(ct * 4 + ks) * 64 + lane];
                acc[ct] = __builtin_amdgcn_mfma_f32_16x16x32_bf16(a, bfrag, acc[ct], 0, 0, 0);
            }
        }
    }

    float bias[8];
    #pragma unroll
    for (int ct = 0; ct < 8; ++ct) bias[ct] = b1[ct * 16 + m];

    float nsq[4] = { 0.f, 0.f, 0.f, 0.f };
    #pragma unroll
    for (int ct = 0; ct < 8; ++ct)
        #pragma unroll
        for (int r = 0; r < 4; ++r) {
            float v = acc[ct][r] + bias[ct];
            acc[ct][r] = v;
            nsq[r] += v * v;
        }
    #pragma unroll
    for (int r = 0; r < 4; ++r) {
        float tt = nsq[r];
        tt += __shfl_xor(tt, 1);
        tt += __shfl_xor(tt, 2);
        tt += __shfl_xor(tt, 4);
        tt += __shfl_xor(tt, 8);
        nsq[r] = 1.0f / fmaxf(sqrtf(tt), 1e-12f);
    }
    // h tile -> LDS in sigma fragment layout: lane (q,m) holds, for each r,
    // the 8 ct-values of row 4q+r at its m. That IS fragment
    // (ks'=m>>2, qq'=m&3, mm'=4q+r), elem j=ct (dim ct*16+m = 16j + ks'*4+qq').
    #pragma unroll
    for (int r = 0; r < 4; ++r) {
        short8 hs;
        #pragma unroll
        for (int ct = 0; ct < 8; ++ct)
            hs[ct] = (short)f2bf(fmaxf(acc[ct][r] * nsq[r], 0.0f));
        hbuf[wave][m >> 2][(m & 3) * 16 + q * 4 + r] = hs;
    }

    // ---- phase C: layer 2 (reads only this wave's hbuf region) ----
    short8 a2[4];
    #pragma unroll
    for (int ks = 0; ks < 4; ++ks) a2[ks] = hbuf[wave][ks][lane];

    const short8* h0 = reinterpret_cast<const short8*>(W2lf);
    const short8* h1 = reinterpret_cast<const short8*>(W2rf);
    float4v accl[3], accr[3];
    #pragma unroll
    for (int ct = 0; ct < 3; ++ct) {
        accl[ct] = (float4v){0.f, 0.f, 0.f, 0.f};
        accr[ct] = (float4v){0.f, 0.f, 0.f, 0.f};
    }
    #pragma unroll
    for (int ks = 0; ks < 4; ++ks) {
        short8 a = a2[ks];
        #pragma unroll
        for (int ct = 0; ct < 3; ++ct) {
            accl[ct] = __builtin_amdgcn_mfma_f32_16x16x32_bf16(a, h0[(ct * 4 + ks) * 64 + lane], accl[ct], 0, 0, 0);
            accr[ct] = __builtin_amdgcn_mfma_f32_16x16x32_bf16(a, h1[(ct * 4 + ks) * 64 + lane], accr[ct], 0, 0, 0);
        }
    }
    #pragma unroll
    for (int r = 0; r < 4; ++r) {
        int node = nb + q * 4 + r;
        if (node < N_NODES) {
            #pragma unroll
            for (int ct = 0; ct < 3; ++ct) {
                int col = ct * 16 + m;
                y2[node * 64 + col] = (u8)f2fp8(accl[ct][r] * 64.0f);
                z[node * 48 + col]  = f2bf(accr[ct][r]);
            }
            y2[node * 64 + 48 + m] = 0;   // zero-pad dims 48..63
        }
    }
}

// ---- Layer-2 aggregation + fused epilogue, 8 nodes/wave, 4-deep pipeline ----
// fp8 y2 rows = 64 B => 8 lanes/row, 8 dims/lane; each lane owns its 8 dims.

__global__ void k_agg2(const u32x2* __restrict__ fp,   // fp8 y2, 8 granules/row
                       const int* __restrict__ csr,
                       const int* __restrict__ row_start,
                       const u16* __restrict__ z,
                       const float* __restrict__ b2,
                       float* __restrict__ out) {
    int lane = threadIdx.x & 63;
    int wave = threadIdx.x >> 6;
    int sub = lane >> 3;      // node within wave 0..7
    int li = lane & 7;        // 8B granule = dims 8li..8li+7
    int n = blockIdx.x * 32 + wave * 8 + sub;
    int s = row_start[n];
    int e = row_start[n + 1];
    f32x2 ac0 = {0.f, 0.f}, ac1 = {0.f, 0.f}, ac2 = {0.f, 0.f}, ac3 = {0.f, 0.f};
#define ACC8(v) do { \
        ac0 += __builtin_amdgcn_cvt_pk_f32_fp8((v).x, false); \
        ac1 += __builtin_amdgcn_cvt_pk_f32_fp8((v).x, true);  \
        ac2 += __builtin_amdgcn_cvt_pk_f32_fp8((v).y, false); \
        ac3 += __builtin_amdgcn_cvt_pk_f32_fp8((v).y, true);  \
    } while (0)
    int p = s;
    u32x2 v0, v1, v2, v3;
    if (p + 4 <= e) {
        int j0 = csr[p], j1 = csr[p + 1], j2 = csr[p + 2], j3 = csr[p + 3];
        v0 = fp[j0 * 8 + li]; v1 = fp[j1 * 8 + li];
        v2 = fp[j2 * 8 + li]; v3 = fp[j3 * 8 + li];
    }
    while (p + 8 <= e) {
        int k0 = csr[p + 4], k1 = csr[p + 5], k2 = csr[p + 6], k3 = csr[p + 7];
        u32x2 w0 = fp[k0 * 8 + li], w1 = fp[k1 * 8 + li];
        u32x2 w2 = fp[k2 * 8 + li], w3 = fp[k3 * 8 + li];
        ACC8(v0); ACC8(v1); ACC8(v2); ACC8(v3);
        v0 = w0; v1 = w1; v2 = w2; v3 = w3;
        p += 4;
    }
    if (p + 4 <= e) { ACC8(v0); ACC8(v1); ACC8(v2); ACC8(v3); p += 4; }
    while (p < e) { u32x2 v = fp[csr[p] * 8 + li]; ACC8(v); ++p; }
#undef ACC8
    float a[8] = { ac0.x, ac0.y, ac1.x, ac1.y, ac2.x, ac2.y, ac3.x, ac3.y };

    // epilogue: each lane owns dims 8li..8li+7 of its node; reductions are
    // xor 1/2/4 within the 8-lane node group. li>=5 lanes contribute zeros.
    float sc = 1.0f / (64.0f * (float)max(e - s, 1));
    float v[8];
    if (li < 5) {
        u32x4 zv = *reinterpret_cast<const u32x4*>(z + n * 48 + li * 8);
        float4v bv0 = *reinterpret_cast<const float4v*>(b2 + li * 8);
        float4v bv1 = *reinterpret_cast<const float4v*>(b2 + li * 8 + 4);
        v[0] = a[0] * sc + bflo(zv.x) + bv0.x;
        v[1] = a[1] * sc + bfhi(zv.x) + bv0.y;
        v[2] = a[2] * sc + bflo(zv.y) + bv0.z;
        v[3] = a[3] * sc + bfhi(zv.y) + bv0.w;
        v[4] = a[4] * sc + bflo(zv.z) + bv1.x;
        v[5] = a[5] * sc + bfhi(zv.z) + bv1.y;
        v[6] = a[6] * sc + bflo(zv.w) + bv1.z;
        v[7] = a[7] * sc + bfhi(zv.w) + bv1.w;
    } else {
        #pragma unroll
        for (int j = 0; j < 8; ++j) v[j] = 0.f;
    }
    float nsq = 0.f;
    #pragma unroll
    for (int j = 0; j < 8; ++j) nsq += v[j] * v[j];
    nsq += __shfl_xor(nsq, 1);
    nsq += __shfl_xor(nsq, 2);
    nsq += __shfl_xor(nsq, 4);
    float rn = 1.0f / fmaxf(sqrtf(nsq), 1e-12f);
    float mv = 0.f;
    #pragma unroll
    for (int j = 0; j < 8; ++j) {
        v[j] = fmaxf(v[j] * rn, 0.f);
        mv = fmaxf(mv, v[j]);
    }
    mv = fmaxf(mv, __shfl_xor(mv, 1));
    mv = fmaxf(mv, __shfl_xor(mv, 2));
    mv = fmaxf(mv, __shfl_xor(mv, 4));
    float se = 0.f;
    if (li < 5) {
        #pragma unroll
        for (int j = 0; j < 8; ++j) se += __expf(v[j] - mv);
    }
    se += __shfl_xor(se, 1);
    se += __shfl_xor(se, 2);
    se += __shfl_xor(se, 4);
    float lse = __logf(se);
    if (li < 5) {
        float4v o0 = { v[0] - mv - lse, v[1] - mv - lse, v[2] - mv - lse, v[3] - mv - lse };
        float4v o1 = { v[4] - mv - lse, v[5] - mv - lse, v[6] - mv - lse, v[7] - mv - lse };
        *reinterpret_cast<float4v*>(out + n * OUT_DIM + li * 8) = o0;
        *reinterpret_cast<float4v*>(out + n * OUT_DIM + li * 8 + 4) = o1;
    }
}

// ---- launch -----------------------------------------------------------------

extern "C" void kernel_launch(void* const* d_in, const int* in_sizes, int n_in,
                              void* d_out, int out_size, void* d_ws, size_t ws_size,
                              hipStream_t stream) {
    const float* x   = (const float*)d_in[0];
    const int*   idx = (const int*)d_in[1];
    const float* W1l = (const float*)d_in[2];
    const float* b1  = (const float*)d_in[3];
    const float* W1r = (const float*)d_in[4];
    const float* W2l = (const float*)d_in[5];
    const float* b2  = (const float*)d_in[6];
    const float* W2r = (const float*)d_in[7];
    float* out = (float*)d_out;

    // Lifetime plan (kernels serialize on one stream):
    //   hist:     R idx        W bucket_size
    //   cvtsc:    R idx,x,W*   W rec, xb, xb8, W*f   (scatter + conversions)
    //   bfill:    R rec        W csr, row_start
    //   agg:      R xb8,csr    W aggb
    //   dense:    R aggb,xb    W y2,z    (y2/z live in rec+xb8 region, both dead)
    //   agg2:     R y2,z,csr   W out
    char* ws = (char*)d_ws;
    int*   bucket_size = (int*)(ws + 0);        // 784 B   } zeroed together
    int*   bucket_cur  = (int*)(ws + 1024);     // 784 B   }
    int*   row_start   = (int*)(ws + 16384);    // (N+1)*4 B
    int*   csr         = (int*)(ws + 1216384);  // 6.4 MB -> ends 7616384
    u16*   xb          = (u16*)(ws + 7616512);  // 25.6 MB bf16(x), read by k_dense
    u16*   aggb        = (u16*)(ws + 33216512); // 25.6 MB (dead after k_dense)
    u64*   rec         = (u64*)(ws + 58816512); // 12.8 MB (dead after k_bfill)
    u32*   xb8         = (u32*)(ws + 71616512); // 12.8 MB fp8(x) (dead after k_agg)
    u8*    y2          = (u8*)(ws + 58816512);  // 6.4 MB  fp8 (over rec, dead)
    u16*   z           = (u16*)(ws + 65216512); // 9.6 MB  (rec tail + xb8 head, both dead)
    u16*   W1lf        = (u16*)(ws + 84416512); // 32768 B (frag-linear)
    u16*   W1rf        = (u16*)(ws + 84449280); // 32768 B
    u16*   W2lf        = (u16*)(ws + 84482048); // 12288 B (frag-linear, sigma k-order, 48 rows)
    u16*   W2rf        = (u16*)(ws + 84494336); // 12288 B

    hipMemsetAsync(ws, 0, 1808, stream);   // bucket_size + bucket_cur

    // tiny histogram first; then bucket-scatter overlapped with all conversions
    k_hist<<<NCHUNK, 256, 0, stream>>>(idx, bucket_size);
    k_cvtsc<<<NCHUNK + XB4 + WB4, 1024, 0, stream>>>(
        x, xb, xb8, W1l, W1r, W2l, W2r, W1lf, W1rf, W2lf, W2rf,
        idx, bucket_size, bucket_cur, rec);
    k_bfill<<<NBUCK, 1024, 0, stream>>>(rec, bucket_size, row_start, csr);

    // layer 1 aggregation (fp8 gather table), 4 nodes/wave, pipelined
    k_agg<<<N_NODES / 16, 256, 0, stream>>>((const u32x2*)xb8, csr, row_start, aggb);
    // fused dense: layer-1 linear+norm+relu -> LDS -> layer-2 projections
    k_dense<<<(N_NODES + 63) / 64, 256, 0, stream>>>(aggb, xb, W1lf, W1rf, W2lf, W2rf, b1, y2, z);
    // layer-2 aggregation with fused epilogue, 8 nodes/wave, 4-deep pipeline
    k_agg2<<<N_NODES / 32, 256, 0, stream>>>((const u32x2*)y2, csr, row_start, z, b2, out);
}